// Round 1
// baseline (22.807 us; speedup 1.0000x reference)
//
#include <hip/hip_runtime.h>

#define KK 784      // 28*28 pixels per image
#define NE 5        // experts

__global__ __launch_bounds__(256, 4) void moe_conv_fused_kernel(
    const float* __restrict__ x,        // [B, 784]
    const int*   __restrict__ cat,      // [B]
    const float* __restrict__ conv_w,   // [5, 784]
    const float* __restrict__ conv_b,   // [5]
    const float* __restrict__ fc1_w,    // [1, 5] -> 5 floats
    const float* __restrict__ fc1_b,    // [1]
    float*       __restrict__ out,      // [B]
    int B)
{
    __shared__ float w_lds[NE * KK];    // 15680 B
    __shared__ float cb_lds[NE];
    __shared__ float fw_lds[NE];

    // cooperative stage of all 5 expert weight rows (float4-vectorized)
    {
        const float4* src = reinterpret_cast<const float4*>(conv_w);
        float4* dst = reinterpret_cast<float4*>(w_lds);
        for (int i = threadIdx.x; i < (NE * KK) / 4; i += blockDim.x)
            dst[i] = src[i];
        if (threadIdx.x < NE) {
            cb_lds[threadIdx.x] = conv_b[threadIdx.x];
            fw_lds[threadIdx.x] = fc1_w[threadIdx.x];
        }
    }
    __syncthreads();

    const float fb = fc1_b[0];
    const int lane   = threadIdx.x & 63;
    const int wave   = (blockIdx.x * blockDim.x + threadIdx.x) >> 6;
    const int nwaves = (gridDim.x * blockDim.x) >> 6;

    for (int s = wave; s < B; s += nwaves) {
        const int e = cat[s];  // uniform across the wave -> broadcast load
        const float4* xv = reinterpret_cast<const float4*>(x + (size_t)s * KK);
        const float4* wv = reinterpret_cast<const float4*>(w_lds + e * KK);

        // 196 float4 per sample: lane, lane+64, lane+128, and lanes 0..3 take 192+lane
        float4 a0 = xv[lane];        float4 b0 = wv[lane];
        float4 a1 = xv[lane + 64];   float4 b1 = wv[lane + 64];
        float4 a2 = xv[lane + 128];  float4 b2 = wv[lane + 128];

        float acc;
        acc  = a0.x * b0.x + a0.y * b0.y + a0.z * b0.z + a0.w * b0.w;
        acc += a1.x * b1.x + a1.y * b1.y + a1.z * b1.z + a1.w * b1.w;
        acc += a2.x * b2.x + a2.y * b2.y + a2.z * b2.z + a2.w * b2.w;
        if (lane < 4) {
            float4 a3 = xv[192 + lane];
            float4 b3 = wv[192 + lane];
            acc += a3.x * b3.x + a3.y * b3.y + a3.z * b3.z + a3.w * b3.w;
        }

        // wave-wide sum (64 lanes)
        #pragma unroll
        for (int off = 32; off > 0; off >>= 1)
            acc += __shfl_down(acc, off, 64);

        if (lane == 0) {
            const float sval = acc + cb_lds[e];       // expert conv scalar
            const float o    = sval * fw_lds[e] + fb; // fc1
            out[s] = o > 0.0f ? o : 0.0f;             // relu
        }
    }
}

extern "C" void kernel_launch(void* const* d_in, const int* in_sizes, int n_in,
                              void* d_out, int out_size, void* d_ws, size_t ws_size,
                              hipStream_t stream) {
    const float* x      = (const float*)d_in[0];
    const int*   cat    = (const int*)d_in[1];
    const float* conv_w = (const float*)d_in[2];
    const float* conv_b = (const float*)d_in[3];
    const float* fc1_w  = (const float*)d_in[4];
    const float* fc1_b  = (const float*)d_in[5];
    float* out = (float*)d_out;

    const int B = in_sizes[1];          // category_indices element count

    const int block = 256;
    int grid = 2048;                    // 256 CU x 8 blocks -> 8192 waves
    const int waves_needed = (B + 0) / 1; // one wave per sample, grid-stride
    (void)waves_needed; (void)d_ws; (void)ws_size; (void)n_in; (void)out_size;
    if (grid * (block / 64) > B) grid = (B + (block / 64) - 1) / (block / 64);

    moe_conv_fused_kernel<<<grid, block, 0, stream>>>(
        x, cat, conv_w, conv_b, fc1_w, fc1_b, out, B);
}